// Round 1
// baseline (9543.604 us; speedup 1.0000x reference)
//
#include <hip/hip_runtime.h>
#include <hip/hip_bf16.h>
#include <math.h>

// Problem dims (fixed by reference)
#define B 128
#define T 64
#define H 512
#define O 47
#define P 4
#define G 2048   // 4*H
#define NL 3

// All recurrent state stored TRANSPOSED: buf[k*B + b], k in [0,H), b in [0,B).
// This gives coalesced lane-per-batch global loads in the gate GEMM and
// coalesced writes in the cell epilogue.

// ---------------------------------------------------------------------------
// init: zero h (ping+pong, 3 layers) and c (3 layers); set nxtT = enc(one-hot(1))
// ---------------------------------------------------------------------------
__global__ __launch_bounds__(256) void init_kernel(
    const float* __restrict__ enc_w,   // [H][O]
    const float* __restrict__ enc_b,   // [H]
    float* __restrict__ nxtT,          // [H][B]
    float* __restrict__ hbufs,         // 6 * H*B
    float* __restrict__ cbufs)         // 3 * H*B
{
    int idx = blockIdx.x * 256 + threadIdx.x;   // 0 .. H*B-1 (grid 256)
    #pragma unroll
    for (int i = 0; i < 6; ++i) hbufs[i * (H*B) + idx] = 0.f;
    #pragma unroll
    for (int i = 0; i < 3; ++i) cbufs[i * (H*B) + idx] = 0.f;
    int h = idx >> 7;                            // idx / B
    nxtT[idx] = enc_w[h * O + 1] + enc_b[h];     // one-hot on symbol 1 through encoder
}

// ---------------------------------------------------------------------------
// precompute: dec_wT[k][o] = dec_w[o][k];  enc_wT[o][h] = enc_w[h][o]
// ---------------------------------------------------------------------------
__global__ __launch_bounds__(256) void transpose_kernel(
    const float* __restrict__ dec_w,   // [O][H]
    const float* __restrict__ enc_w,   // [H][O]
    float* __restrict__ dec_wT,        // [H][O]
    float* __restrict__ enc_wT)        // [O][H]
{
    int idx = blockIdx.x * 256 + threadIdx.x;
    if (idx < O * H) {
        int o = idx / H, k = idx - o * H;
        dec_wT[k * O + o] = dec_w[o * H + k];
        enc_wT[o * H + k] = enc_w[k * O + o];
    }
}

// ---------------------------------------------------------------------------
// gates: one LSTM layer (GEMM over x-part and h-part + fused cell update).
// grid = 256 WGs: wg = bg(2) x jg(128). WG owns 4 hidden units (16 gate rows)
// for 64 batches. block = 512 threads: (ks in [0,8)) x (b in [0,64));
// ks is wave-uniform (tid>>6). Each thread: 16-row register tile, k-slice of 64
// per pass, x streamed from global (coalesced, reused across 16 rows).
// ---------------------------------------------------------------------------
__global__ __launch_bounds__(512) void gates_kernel(
    const float* __restrict__ xT,      // [H][B] input (nxt or h_below)
    const float* __restrict__ hT,      // [H][B] this layer's h(t-1)
    const float* __restrict__ w_ih,    // [G][ldih]
    int ldih,                          // 516 for layer0 (cols 512..515 = props), else 512
    const float* __restrict__ w_hh,    // [G][H]
    const float* __restrict__ b_ih,    // [G]
    const float* __restrict__ b_hh,    // [G]
    const float* __restrict__ props,   // [B][P] or nullptr
    float* __restrict__ c,             // [H][B] in/out (this layer)
    float* __restrict__ hout)          // [H][B] h(t) out (ping-pong, != hT)
{
    const int wg = blockIdx.x;
    const int bg = wg >> 7;            // batch group 0/1
    const int jg = wg & 127;           // hidden-unit group
    const int m0 = jg * 4;
    const int lane_b = threadIdx.x & 63;
    const int ks = threadIdx.x >> 6;   // 0..7, wave-uniform
    const int bb = (bg << 6) + lane_b; // global batch 0..127

    float acc[16];
    #pragma unroll
    for (int r = 0; r < 16; ++r) acc[r] = 0.f;

    const float* wih_rows[16];
    const float* whh_rows[16];
    #pragma unroll
    for (int q = 0; q < 4; ++q)
        #pragma unroll
        for (int mi = 0; mi < 4; ++mi) {
            int r = q * 4 + mi;
            int j = q * H + m0 + mi;
            wih_rows[r] = w_ih + (size_t)j * ldih;
            whh_rows[r] = w_hh + (size_t)j * H;
        }

    const int kbeg = ks * 64, kend = ks * 64 + 64;

    // pass A: x-part (K = 512)
    for (int k0 = kbeg; k0 < kend; k0 += 4) {
        float x0 = xT[(k0 + 0) * B + bb];
        float x1 = xT[(k0 + 1) * B + bb];
        float x2 = xT[(k0 + 2) * B + bb];
        float x3 = xT[(k0 + 3) * B + bb];
        #pragma unroll
        for (int r = 0; r < 16; ++r) {
            float4 wv = *(const float4*)(wih_rows[r] + k0);
            acc[r] += wv.x * x0 + wv.y * x1 + wv.z * x2 + wv.w * x3;
        }
    }
    // pass B: h-part (K = 512)
    for (int k0 = kbeg; k0 < kend; k0 += 4) {
        float x0 = hT[(k0 + 0) * B + bb];
        float x1 = hT[(k0 + 1) * B + bb];
        float x2 = hT[(k0 + 2) * B + bb];
        float x3 = hT[(k0 + 3) * B + bb];
        #pragma unroll
        for (int r = 0; r < 16; ++r) {
            float4 wv = *(const float4*)(whh_rows[r] + k0);
            acc[r] += wv.x * x0 + wv.y * x1 + wv.z * x2 + wv.w * x3;
        }
    }

    // cross-slice reduction + fused LSTM cell
    __shared__ float gbuf[16][8][64];   // 32 KB
    #pragma unroll
    for (int r = 0; r < 16; ++r) gbuf[r][ks][lane_b] = acc[r];
    __syncthreads();

    if (threadIdx.x < 256) {
        int mi = threadIdx.x >> 6;         // 0..3
        int b  = threadIdx.x & 63;
        int bbo = (bg << 6) + b;
        int m = m0 + mi;
        float g[4];
        #pragma unroll
        for (int q = 0; q < 4; ++q) {
            int j = q * H + m;
            float s = b_ih[j] + b_hh[j];
            #pragma unroll
            for (int k2 = 0; k2 < 8; ++k2) s += gbuf[q * 4 + mi][k2][b];
            if (props) {  // layer0: props columns live at w_ih[j][512..515]
                const float* wp = w_ih + (size_t)j * ldih + H;
                const float* pp = props + bbo * P;
                s += wp[0] * pp[0] + wp[1] * pp[1] + wp[2] * pp[2] + wp[3] * pp[3];
            }
            g[q] = s;
        }
        // torch gate order: i, f, g, o
        float ig = 1.f / (1.f + expf(-g[0]));
        float fg = 1.f / (1.f + expf(-g[1]));
        float gv = tanhf(g[2]);
        float og = 1.f / (1.f + expf(-g[3]));
        int idx = m * B + bbo;
        float cn = fg * c[idx] + ig * gv;
        c[idx] = cn;
        hout[idx] = og * tanhf(cn);
    }
}

// ---------------------------------------------------------------------------
// dec+enc feedback: logits = h2 @ dec_w^T + dec_b (written to out[b][t][:]);
// nxt = logits @ enc_w^T + enc_b (written transposed). One WG per batch.
// ---------------------------------------------------------------------------
__global__ __launch_bounds__(256) void decenc_kernel(
    const float* __restrict__ h2T,     // [H][B]
    const float* __restrict__ dec_wT,  // [H][O]
    const float* __restrict__ dec_b,   // [O]
    const float* __restrict__ enc_wT,  // [O][H]
    const float* __restrict__ enc_b,   // [H]
    float* __restrict__ nxtT,          // [H][B]
    float* __restrict__ out,           // [B][T][O]
    int t)
{
    const int b = blockIdx.x;
    const int w = threadIdx.x >> 6;    // 0..3 (k-slice)
    const int o = threadIdx.x & 63;

    __shared__ float red[4][64];
    __shared__ float lg[64];

    float p = 0.f;
    if (o < O) {
        for (int k = w * 128; k < w * 128 + 128; ++k)
            p += h2T[k * B + b] * dec_wT[k * O + o];
    }
    red[w][o] = p;
    __syncthreads();

    if (threadIdx.x < 64) {
        int oo = threadIdx.x;
        float s = 0.f;
        if (oo < O) {
            s = dec_b[oo] + red[0][oo] + red[1][oo] + red[2][oo] + red[3][oo];
            out[((size_t)b * T + t) * O + oo] = s;
        }
        lg[oo] = s;
    }
    __syncthreads();

    for (int h = threadIdx.x; h < H; h += 256) {
        float s = enc_b[h];
        #pragma unroll 1
        for (int oo = 0; oo < O; ++oo)
            s += lg[oo] * enc_wT[oo * H + h];
        nxtT[h * B + b] = s;
    }
}

// ---------------------------------------------------------------------------
extern "C" void kernel_launch(void* const* d_in, const int* in_sizes, int n_in,
                              void* d_out, int out_size, void* d_ws, size_t ws_size,
                              hipStream_t stream) {
    // setup_inputs() order:
    // 0:x 1:properties 2:enc_w 3:enc_b 4:dec_w 5:dec_b 6:w_ih0 7:w_hh0
    // 8:b_ih0 9:b_hh0 10:w_ih_rest 11:w_hh_rest 12:b_ih_rest 13:b_hh_rest
    const float* props = (const float*)d_in[1];
    const float* enc_w = (const float*)d_in[2];
    const float* enc_b = (const float*)d_in[3];
    const float* dec_w = (const float*)d_in[4];
    const float* dec_b = (const float*)d_in[5];
    const float* w_ih0 = (const float*)d_in[6];
    const float* w_hh0 = (const float*)d_in[7];
    const float* b_ih0 = (const float*)d_in[8];
    const float* b_hh0 = (const float*)d_in[9];
    const float* w_ihr = (const float*)d_in[10];
    const float* w_hhr = (const float*)d_in[11];
    const float* b_ihr = (const float*)d_in[12];
    const float* b_hhr = (const float*)d_in[13];

    const int HB = H * B;                    // 65536 floats
    float* ws     = (float*)d_ws;
    float* nxtT   = ws;                      // HB
    float* hb     = ws + HB;                 // 6*HB (3 layers x ping/pong)
    float* cb     = ws + 7 * HB;             // 3*HB
    float* dec_wT = ws + 10 * HB;            // H*O
    float* enc_wT = dec_wT + H * O;          // O*H

    init_kernel<<<256, 256, 0, stream>>>(enc_w, enc_b, nxtT, hb, cb);
    transpose_kernel<<<(O * H + 255) / 256, 256, 0, stream>>>(dec_w, enc_w, dec_wT, enc_wT);

    float* hprev[NL];
    float* hcur[NL];
    for (int l = 0; l < NL; ++l) {
        hprev[l] = hb + (2 * l) * HB;
        hcur[l]  = hb + (2 * l + 1) * HB;
    }

    for (int t = 0; t < T; ++t) {
        gates_kernel<<<256, 512, 0, stream>>>(
            nxtT, hprev[0], w_ih0, H + P, w_hh0, b_ih0, b_hh0, props,
            cb + 0 * HB, hcur[0]);
        gates_kernel<<<256, 512, 0, stream>>>(
            hcur[0], hprev[1], w_ihr, H, w_hhr, b_ihr, b_hhr, nullptr,
            cb + 1 * HB, hcur[1]);
        gates_kernel<<<256, 512, 0, stream>>>(
            hcur[1], hprev[2], w_ihr + (size_t)G * H, H, w_hhr + (size_t)G * H,
            b_ihr + G, b_hhr + G, nullptr, cb + 2 * HB, hcur[2]);
        decenc_kernel<<<B, 256, 0, stream>>>(
            hcur[2], dec_wT, dec_b, enc_wT, enc_b, nxtT, (float*)d_out, t);
        for (int l = 0; l < NL; ++l) {
            float* tmp = hprev[l]; hprev[l] = hcur[l]; hcur[l] = tmp;
        }
    }
}